// Round 4
// baseline (3500.956 us; speedup 1.0000x reference)
//
#include <hip/hip_runtime.h>
#include <hip/hip_bf16.h>
#include <math.h>

#define SEQ 512
#define NB  64
#define NIN 512
#define NH  1024
#define NO  512

typedef __bf16 bf16x8 __attribute__((ext_vector_type(8)));
typedef float  f32x4  __attribute__((ext_vector_type(4)));

union QPair { unsigned long long u[2]; bf16x8 v; };

__device__ __forceinline__ f32x4 mfma16(bf16x8 a, bf16x8 b, f32x4 c) {
  return __builtin_amdgcn_mfma_f32_16x16x32_bf16(a, b, c, 0, 0, 0);
}

// Persistent RNN kernel, IF-coherent exchange, pipelined coherent loads.
// Grid: 256 WGs = 4 groups (16 batches) x 64 WGs (16-col j-slice of H).
// Each WG: 256 threads = 4 waves, K split 4 ways (wave wv: H-k in
// [wv*256,+256), IN-k in [wv*128,+128)).
// Weights in registers as bf16 hi/lo fragments; __launch_bounds__(256,1)
// so the allocator does NOT spill them (R3's (256,2) spilled at VGPR=124).
// h exchanged as bf16 hi/lo PLANES via agent-scope relaxed atomics
// (write-through to Infinity Cache; loads bypass stale L1/L2). Reader
// stages all 32 b64 loads before any use -> single pipelined IF round-trip.
// Each wave spins only on the 16 flags of the WGs producing its K-quarter.
// LDS reduce buffers are double-buffered by t&1 (flag transitivity makes
// distance-2 reuse safe, distance-1 is not).
__global__ __launch_bounds__(256, 1)
void rnn_persistent(const float* __restrict__ x, const float* __restrict__ h0,
                    const float* __restrict__ i_h, const float* __restrict__ h_h,
                    const float* __restrict__ h_o, const float* __restrict__ b_i,
                    const float* __restrict__ b_o, float* __restrict__ out,
                    int* __restrict__ flags, __bf16* __restrict__ hbuf) {
  const int bid  = blockIdx.x;
  const int g    = bid & 3;          // group id (batch slice)
  const int w    = bid >> 2;         // 0..63  (hidden-column slice)
  const int wv   = threadIdx.x >> 6; // wave 0..3
  const int lane = threadIdx.x & 63;
  const int tn   = lane & 15;        // A-row (batch) / C-col index
  const int tq   = lane >> 4;        // k-subblock / C-row-block index
  const int Bg   = g * 16;
  const int Jw   = w * 16;
  const int Ow   = w * 8;
  const int kb0  = wv * 256;         // this wave's H-k base
  const int xb0  = wv * 128;         // this wave's IN-k base

  // [parity][wave-1][r*64+lane] stride-1 layout (no bank conflicts)
  __shared__ float red_h[2][3 * 256];
  __shared__ float red_o[2][3 * 256];

  // ---- invariant weight fragments in registers (bf16 hi/lo split) ----
  bf16x8 whi[8], wlo[8], hof[8], ihhi[4], ihlo[4];
#pragma unroll
  for (int c = 0; c < 8; ++c) {
    const int kb = kb0 + c * 32 + tq * 8;
#pragma unroll
    for (int j = 0; j < 8; ++j) {
      float v = h_h[(kb + j) * NH + Jw + tn];
      __bf16 hi = (__bf16)v;
      whi[c][j] = hi;
      wlo[c][j] = (__bf16)(v - (float)hi);
      float vo = (tn < 8) ? h_o[(kb + j) * NO + Ow + tn] : 0.0f;
      hof[c][j] = (__bf16)vo;
    }
  }
#pragma unroll
  for (int c = 0; c < 4; ++c) {
    const int kb = xb0 + c * 32 + tq * 8;
#pragma unroll
    for (int j = 0; j < 8; ++j) {
      float v = i_h[(kb + j) * NH + Jw + tn];
      __bf16 hi = (__bf16)v;
      ihhi[c][j] = hi;
      ihlo[c][j] = (__bf16)(v - (float)hi);
    }
  }
  const float bi = b_i[Jw + tn];
  const float bo = (tn < 8) ? b_o[Ow + tn] : 0.0f;

  int* fl = flags + g * 64;
  __bf16* hb = hbuf;  // [parity][hi/lo plane][64 rows][1024 cols] bf16
  const int myflag = wv * 16 + (lane & 15);  // this wave's producer set
  const int rowoff = (Bg + tn) * NH + kb0 + tq * 8;

  // ---- init: wave 0 publishes h0 slice into parity-0 planes ----
  if (wv == 0) {
#pragma unroll
    for (int r = 0; r < 4; ++r) {
      const int row = Bg + tq * 4 + r;
      float v = h0[row * NH + Jw + tn];
      __bf16 hi = (__bf16)v;
      __bf16 lo = (__bf16)(v - (float)hi);
      __hip_atomic_store((short*)(hb + row * NH + Jw + tn),
                         __builtin_bit_cast(short, hi),
                         __ATOMIC_RELAXED, __HIP_MEMORY_SCOPE_AGENT);
      __hip_atomic_store((short*)(hb + 65536 + row * NH + Jw + tn),
                         __builtin_bit_cast(short, lo),
                         __ATOMIC_RELAXED, __HIP_MEMORY_SCOPE_AGENT);
    }
    asm volatile("s_waitcnt vmcnt(0)" ::: "memory");
    if (lane == 0)
      __hip_atomic_store(&fl[w], 1, __ATOMIC_RELAXED, __HIP_MEMORY_SCOPE_AGENT);
  }

  for (int t = 0; t < SEQ; ++t) {
    f32x4 acc_h = {0.f, 0.f, 0.f, 0.f};
    f32x4 acc_o = {0.f, 0.f, 0.f, 0.f};

    // ---- xi contribution first (independent of h_t, overlaps the wait) ----
#pragma unroll
    for (int c = 0; c < 4; ++c) {
      const int k = xb0 + c * 32 + tq * 8;
      const float* xp = x + (size_t)(t * NB + Bg + tn) * NIN + k;
      f32x4 xa = *(const f32x4*)xp;
      f32x4 xb2 = *(const f32x4*)(xp + 4);
      bf16x8 xhi, xlo;
#pragma unroll
      for (int e = 0; e < 4; ++e) {
        __bf16 h1 = (__bf16)xa[e];
        xhi[e] = h1; xlo[e] = (__bf16)(xa[e] - (float)h1);
        __bf16 h2 = (__bf16)xb2[e];
        xhi[4 + e] = h2; xlo[4 + e] = (__bf16)(xb2[e] - (float)h2);
      }
      acc_h = mfma16(xhi, ihhi[c], acc_h);
      acc_h = mfma16(xlo, ihhi[c], acc_h);
      acc_h = mfma16(xhi, ihlo[c], acc_h);
    }

    // ---- wait for THIS WAVE's 16 producer WGs only ----
    {
      const int tgt = t + 1;
      while (true) {
        int v = __hip_atomic_load(&fl[myflag], __ATOMIC_RELAXED, __HIP_MEMORY_SCOPE_AGENT);
        if (__all(v >= tgt)) break;
      }
    }

    // ---- stage ALL coherent loads (pipelined single round-trip) ----
    const __bf16* Hhi = hb + (t & 1) * 131072;
    const __bf16* Hlo = Hhi + 65536;
    unsigned long long qh[16], ql[16];
#pragma unroll
    for (int c = 0; c < 8; ++c) {
      const unsigned long long* ph = (const unsigned long long*)(Hhi + rowoff + c * 32);
      qh[2 * c]     = __hip_atomic_load(ph,     __ATOMIC_RELAXED, __HIP_MEMORY_SCOPE_AGENT);
      qh[2 * c + 1] = __hip_atomic_load(ph + 1, __ATOMIC_RELAXED, __HIP_MEMORY_SCOPE_AGENT);
    }
#pragma unroll
    for (int c = 0; c < 8; ++c) {
      const unsigned long long* pl = (const unsigned long long*)(Hlo + rowoff + c * 32);
      ql[2 * c]     = __hip_atomic_load(pl,     __ATOMIC_RELAXED, __HIP_MEMORY_SCOPE_AGENT);
      ql[2 * c + 1] = __hip_atomic_load(pl + 1, __ATOMIC_RELAXED, __HIP_MEMORY_SCOPE_AGENT);
    }

    // ---- h-mix + fused output projection (zero unpack VALU) ----
#pragma unroll
    for (int c = 0; c < 8; ++c) {
      QPair a, b;
      a.u[0] = qh[2 * c]; a.u[1] = qh[2 * c + 1];
      b.u[0] = ql[2 * c]; b.u[1] = ql[2 * c + 1];
      acc_h = mfma16(a.v, whi[c], acc_h);
      acc_h = mfma16(b.v, whi[c], acc_h);
      acc_h = mfma16(a.v, wlo[c], acc_h);
      acc_o = mfma16(a.v, hof[c], acc_o);
      acc_o = mfma16(b.v, hof[c], acc_o);
    }

    // ---- combine the 4 waves' K-partials (double-buffered LDS) ----
    const int par = t & 1;
    if (wv > 0) {
      const int base = (wv - 1) * 256 + lane;
#pragma unroll
      for (int r = 0; r < 4; ++r) {
        red_h[par][base + r * 64] = acc_h[r];
        red_o[par][base + r * 64] = acc_o[r];
      }
    }
    __syncthreads();
    if (wv == 0) {
      // critical path first: reduce h, tanh, publish planes, flag
#pragma unroll
      for (int p = 0; p < 3; ++p)
#pragma unroll
        for (int r = 0; r < 4; ++r) acc_h[r] += red_h[par][p * 256 + r * 64 + lane];

      __bf16* Nhi = hb + ((t + 1) & 1) * 131072;
      __bf16* Nlo = Nhi + 65536;
      float hv[4];
#pragma unroll
      for (int r = 0; r < 4; ++r) {
        const int row = Bg + tq * 4 + r;
        float v = tanhf(acc_h[r] + bi);
        hv[r] = v;
        __bf16 hi = (__bf16)v;
        __bf16 lo = (__bf16)(v - (float)hi);
        __hip_atomic_store((short*)(Nhi + row * NH + Jw + tn),
                           __builtin_bit_cast(short, hi),
                           __ATOMIC_RELAXED, __HIP_MEMORY_SCOPE_AGENT);
        __hip_atomic_store((short*)(Nlo + row * NH + Jw + tn),
                           __builtin_bit_cast(short, lo),
                           __ATOMIC_RELAXED, __HIP_MEMORY_SCOPE_AGENT);
      }
      asm volatile("s_waitcnt vmcnt(0)" ::: "memory");
      if (lane == 0)
        __hip_atomic_store(&fl[w], t + 2, __ATOMIC_RELAXED, __HIP_MEMORY_SCOPE_AGENT);

      // off critical path: o_{t-1} and h_final
#pragma unroll
      for (int p = 0; p < 3; ++p)
#pragma unroll
        for (int r = 0; r < 4; ++r) acc_o[r] += red_o[par][p * 256 + r * 64 + lane];
      if (t >= 1 && tn < 8) {
#pragma unroll
        for (int r = 0; r < 4; ++r) {
          const int row = Bg + tq * 4 + r;
          float o = acc_o[r] + bo;
          o = (o >= 0.f) ? o : 0.01f * o;
          out[((size_t)(t - 1) * NB + row) * NO + Ow + tn] = o;
        }
      }
      if (t == SEQ - 1) {
#pragma unroll
        for (int r = 0; r < 4; ++r) {
          const int row = Bg + tq * 4 + r;
          out[(size_t)SEQ * NB * NO + row * NH + Jw + tn] = hv[r];
        }
      }
    }
  }

  // ---- epilogue: o_{SEQ-1} from h_state[SEQ] (parity 0) ----
  {
    const int tgt = SEQ + 1;
    while (true) {
      int v = __hip_atomic_load(&fl[myflag], __ATOMIC_RELAXED, __HIP_MEMORY_SCOPE_AGENT);
      if (__all(v >= tgt)) break;
    }
    const __bf16* Hhi = hb + (SEQ & 1) * 131072;
    const __bf16* Hlo = Hhi + 65536;
    unsigned long long qh[16], ql[16];
#pragma unroll
    for (int c = 0; c < 8; ++c) {
      const unsigned long long* ph = (const unsigned long long*)(Hhi + rowoff + c * 32);
      qh[2 * c]     = __hip_atomic_load(ph,     __ATOMIC_RELAXED, __HIP_MEMORY_SCOPE_AGENT);
      qh[2 * c + 1] = __hip_atomic_load(ph + 1, __ATOMIC_RELAXED, __HIP_MEMORY_SCOPE_AGENT);
      const unsigned long long* pl = (const unsigned long long*)(Hlo + rowoff + c * 32);
      ql[2 * c]     = __hip_atomic_load(pl,     __ATOMIC_RELAXED, __HIP_MEMORY_SCOPE_AGENT);
      ql[2 * c + 1] = __hip_atomic_load(pl + 1, __ATOMIC_RELAXED, __HIP_MEMORY_SCOPE_AGENT);
    }
    f32x4 acc_o = {0.f, 0.f, 0.f, 0.f};
#pragma unroll
    for (int c = 0; c < 8; ++c) {
      QPair a, b;
      a.u[0] = qh[2 * c]; a.u[1] = qh[2 * c + 1];
      b.u[0] = ql[2 * c]; b.u[1] = ql[2 * c + 1];
      acc_o = mfma16(a.v, hof[c], acc_o);
      acc_o = mfma16(b.v, hof[c], acc_o);
    }
    if (wv > 0) {
      const int base = (wv - 1) * 256 + lane;
#pragma unroll
      for (int r = 0; r < 4; ++r) red_o[0][base + r * 64] = acc_o[r];
    }
    __syncthreads();
    if (wv == 0 && tn < 8) {
#pragma unroll
      for (int r = 0; r < 4; ++r) {
        float s = acc_o[r];
#pragma unroll
        for (int p = 0; p < 3; ++p) s += red_o[0][p * 256 + r * 64 + lane];
        const int row = Bg + tq * 4 + r;
        float o = s + bo;
        o = (o >= 0.f) ? o : 0.01f * o;
        out[((size_t)(SEQ - 1) * NB + row) * NO + Ow + tn] = o;
      }
    }
  }
}

extern "C" void kernel_launch(void* const* d_in, const int* in_sizes, int n_in,
                              void* d_out, int out_size, void* d_ws, size_t ws_size,
                              hipStream_t stream) {
  (void)in_sizes; (void)n_in; (void)out_size; (void)ws_size;
  const float* x   = (const float*)d_in[0];
  const float* h0  = (const float*)d_in[1];
  const float* i_h = (const float*)d_in[2];
  const float* h_h = (const float*)d_in[3];
  const float* h_o = (const float*)d_in[4];
  const float* b_i = (const float*)d_in[5];
  const float* b_o = (const float*)d_in[6];
  float* out = (float*)d_out;
  int* flags = (int*)d_ws;                        // 256 ints
  __bf16* hbuf = (__bf16*)((char*)d_ws + 4096);   // 2 par x 2 planes x 64x1024 bf16 = 512 KB

  hipMemsetAsync(d_ws, 0, 1024, stream);

  void* args[] = {&x, &h0, &i_h, &h_h, &h_o, &b_i, &b_o, &out, &flags, &hbuf};
  hipError_t err = hipLaunchCooperativeKernel((const void*)rnn_persistent,
                                              dim3(256), dim3(256), args, 0, stream);
  if (err != hipSuccess) {
    // Plain launch fallback: protocol only needs co-residency (grid 256 <=
    // 1 block/CU capacity at this footprint).
    rnn_persistent<<<dim3(256), dim3(256), 0, stream>>>(
        x, h0, i_h, h_h, h_o, b_i, b_o, out, flags, hbuf);
  }
}

// Round 7
// 3142.838 us; speedup vs baseline: 1.1139x; 1.1139x over previous
//
#include <hip/hip_runtime.h>
#include <hip/hip_bf16.h>
#include <math.h>

#define SEQ 512
#define NB  64
#define NIN 512
#define NH  1024
#define NO  512

typedef __bf16 bf16x8 __attribute__((ext_vector_type(8)));
typedef float  f32x4  __attribute__((ext_vector_type(4)));

__device__ __forceinline__ f32x4 mfma16(bf16x8 a, bf16x8 b, f32x4 c) {
  return __builtin_amdgcn_mfma_f32_16x16x32_bf16(a, b, c, 0, 0, 0);
}

// Step-tag offset: h in (-1,1) is stored as h + K, K in {4,8} flipping on
// each reuse of a depth-2 buffer. A float is "step-t data" iff |f-K(t)|<2.
// Stale data (other K) is >=3 away; 0xAA poison ~3e-13; NaN fails all
// compares. Torn/partial writes self-reject per-float. => No flags, no
// fences, no vmcnt-ack anywhere on the critical path.
__device__ __forceinline__ float kc(int t) {
  return 4.0f + 4.0f * (float)((t >> 1) & 1);
}

#define SPIN_LIM 20000  // ~5ms per wait; visible FAIL, never a watchdog hang

// Persistent RNN, value-tagged fp32 exchange (R4 grid/shape: proven launch).
// Grid: 256 WGs = 4 groups (16 batches) x 64 WGs (16-col j-slice of H).
// Each WG: 256 threads = 4 waves = 4 K-quarters. Weights register-resident
// as bf16 hi/lo fragments. h exchanged as fp32 (h + K(t)) in a depth-2
// buffer via agent-scope relaxed atomics (proven cross-XCD coherent in R4).
// Consumer: pipelined load of its 64 floats + per-float range check; retry
// until all valid -- at which point the data is already in registers.
// Safety: writing h_{t+3} requires all WGs consumed h_{t+1} (lockstep
// causality), so depth-2 has no WAR hazard and readers never see future K.
__global__ __launch_bounds__(256, 1)
void rnn_vt(const float* __restrict__ x, const float* __restrict__ h0,
            const float* __restrict__ i_h, const float* __restrict__ h_h,
            const float* __restrict__ h_o, const float* __restrict__ b_i,
            const float* __restrict__ b_o, float* __restrict__ out,
            float* __restrict__ hbuf) {
  const int bid  = blockIdx.x;
  const int g    = bid & 3;          // group id (batch slice)
  const int w    = bid >> 2;         // 0..63  (hidden-column slice)
  const int wv   = threadIdx.x >> 6; // wave 0..3 = K-quarter
  const int lane = threadIdx.x & 63;
  const int tn   = lane & 15;        // MFMA A-row (batch) / C col
  const int tq   = lane >> 4;        // MFMA k-sub / C row-block
  const int Bg   = g * 16;
  const int Jw   = w * 16;
  const int Ow   = w * 8;
  const int kb0  = wv * 256;         // this wave's H-k base
  const int xb0  = wv * 128;         // this wave's IN-k base

  __shared__ float red_h[2][3][256]; // [parity][wave-1][r*64+lane]
  __shared__ float red_o[2][3][256];
  __shared__ int   sh_dead;
  if (threadIdx.x == 0) sh_dead = 0;

  // ---- invariant weight fragments in registers (bf16 hi/lo split) ----
  bf16x8 whi[8], wlo[8], hof[8], ihhi[4], ihlo[4];
#pragma unroll
  for (int c = 0; c < 8; ++c) {
    const int kb = kb0 + c * 32 + tq * 8;
#pragma unroll
    for (int j = 0; j < 8; ++j) {
      float v = h_h[(kb + j) * NH + Jw + tn];
      __bf16 hi = (__bf16)v;
      whi[c][j] = hi;
      wlo[c][j] = (__bf16)(v - (float)hi);
      float vo = (tn < 8) ? h_o[(kb + j) * NO + Ow + tn] : 0.0f;
      hof[c][j] = (__bf16)vo;
    }
  }
#pragma unroll
  for (int c = 0; c < 4; ++c) {
    const int kb = xb0 + c * 32 + tq * 8;
#pragma unroll
    for (int j = 0; j < 8; ++j) {
      float v = i_h[(kb + j) * NH + Jw + tn];
      __bf16 hi = (__bf16)v;
      ihhi[c][j] = hi;
      ihlo[c][j] = (__bf16)(v - (float)hi);
    }
  }
  const float bi = b_i[Jw + tn];
  const float bo = (tn < 8) ? b_o[Ow + tn] : 0.0f;

  float* hb = hbuf;  // [2 parity][64 rows][1024 cols] fp32, value-tagged
  const int rowoff = (Bg + tn) * NH + kb0 + tq * 8;  // this lane's A-frag base

  __syncthreads();  // sh_dead visible

  // ---- init: wave 0 publishes h0 slice (tagged K(0)) into parity 0 ----
  if (wv == 0) {
#pragma unroll
    for (int r = 0; r < 4; ++r) {
      const int row = Bg + tq * 4 + r;
      __hip_atomic_store(&hb[row * NH + Jw + tn],
                         h0[row * NH + Jw + tn] + kc(0),
                         __ATOMIC_RELAXED, __HIP_MEMORY_SCOPE_AGENT);
    }
  }

  for (int t = 0; t < SEQ; ++t) {
    f32x4 acc_h = {0.f, 0.f, 0.f, 0.f};
    f32x4 acc_o = {0.f, 0.f, 0.f, 0.f};

    // ---- xi = x @ i_h (independent of h_t; overlaps others' tail) ----
#pragma unroll
    for (int c = 0; c < 4; ++c) {
      const float* xp = x + (size_t)(t * NB + Bg + tn) * NIN + xb0 + c * 32 + tq * 8;
      f32x4 xa = *(const f32x4*)xp;
      f32x4 xb2 = *(const f32x4*)(xp + 4);
      bf16x8 xhi, xlo;
#pragma unroll
      for (int e = 0; e < 4; ++e) {
        __bf16 h1 = (__bf16)xa[e];
        xhi[e] = h1; xlo[e] = (__bf16)(xa[e] - (float)h1);
        __bf16 h2 = (__bf16)xb2[e];
        xhi[4 + e] = h2; xlo[4 + e] = (__bf16)(xb2[e] - (float)h2);
      }
      acc_h = mfma16(xhi, ihhi[c], acc_h);
      acc_h = mfma16(xlo, ihhi[c], acc_h);
      acc_h = mfma16(xhi, ihlo[c], acc_h);
    }

    // ---- poll-load this lane's 64 h floats until all carry tag K(t) ----
    const float Kt = kc(t);
    const float* hP = hb + (t & 1) * 65536;
    unsigned long long q[32];
    int trip = 0;
    {
      int iter = 0;
      while (true) {
#pragma unroll
        for (int c = 0; c < 8; ++c) {
          const unsigned long long* p = (const unsigned long long*)(hP + rowoff + c * 32);
#pragma unroll
          for (int u = 0; u < 4; ++u)
            q[4 * c + u] = __hip_atomic_load(p + u, __ATOMIC_RELAXED,
                                             __HIP_MEMORY_SCOPE_AGENT);
        }
        float mn = 1e30f, mx = -1e30f;
#pragma unroll
        for (int i = 0; i < 32; ++i) {
          float f0 = __builtin_bit_cast(float, (unsigned)(q[i] & 0xffffffffull));
          float f1 = __builtin_bit_cast(float, (unsigned)(q[i] >> 32));
          mn = fminf(mn, fminf(f0, f1));
          mx = fmaxf(mx, fmaxf(f0, f1));
        }
        bool ok = (mn > Kt - 2.0f) && (mx < Kt + 2.0f);
        if (__all(ok)) break;
        if (++iter > SPIN_LIM) { trip = 1; break; }
      }
    }

    // ---- untag + split to bf16 hi/lo A-frags, then MFMA ----
#pragma unroll
    for (int c = 0; c < 8; ++c) {
      bf16x8 ahi, alo;
#pragma unroll
      for (int u = 0; u < 4; ++u) {
        unsigned long long qq = q[4 * c + u];
        float f0 = __builtin_bit_cast(float, (unsigned)(qq & 0xffffffffull)) - Kt;
        float f1 = __builtin_bit_cast(float, (unsigned)(qq >> 32)) - Kt;
        __bf16 b0 = (__bf16)f0;
        ahi[2 * u] = b0; alo[2 * u] = (__bf16)(f0 - (float)b0);
        __bf16 b1 = (__bf16)f1;
        ahi[2 * u + 1] = b1; alo[2 * u + 1] = (__bf16)(f1 - (float)b1);
      }
      acc_h = mfma16(ahi, whi[c], acc_h);
      acc_h = mfma16(alo, whi[c], acc_h);
      acc_h = mfma16(ahi, wlo[c], acc_h);
      acc_o = mfma16(ahi, hof[c], acc_o);
      acc_o = mfma16(alo, hof[c], acc_o);
    }

    // ---- cross-wave K reduction (parity double-buffered LDS) ----
    const int par = t & 1;
    if (wv > 0) {
      const int base = (wv - 1);
#pragma unroll
      for (int r = 0; r < 4; ++r) {
        red_h[par][base][r * 64 + lane] = acc_h[r];
        red_o[par][base][r * 64 + lane] = acc_o[r];
      }
    }
    if (trip) sh_dead = 1;
    __syncthreads();
    if (sh_dead) break;  // WG-uniform bail -> fast visible FAIL, no hang

    if (wv == 0) {
      // critical path: reduce h, tanh, publish tagged h_{t+1}
#pragma unroll
      for (int s = 0; s < 3; ++s)
#pragma unroll
        for (int r = 0; r < 4; ++r) acc_h[r] += red_h[par][s][r * 64 + lane];

      float* nP = hb + ((t + 1) & 1) * 65536;
      const float Kn = kc(t + 1);
      float hv[4];
#pragma unroll
      for (int r = 0; r < 4; ++r) {
        const int row = Bg + tq * 4 + r;
        float v = tanhf(acc_h[r] + bi);
        hv[r] = v;
        __hip_atomic_store(&nP[row * NH + Jw + tn], v + Kn,
                           __ATOMIC_RELAXED, __HIP_MEMORY_SCOPE_AGENT);
      }

      // off critical path: o_{t-1} and h_final
#pragma unroll
      for (int s = 0; s < 3; ++s)
#pragma unroll
        for (int r = 0; r < 4; ++r) acc_o[r] += red_o[par][s][r * 64 + lane];
      if (t >= 1 && tn < 8) {
#pragma unroll
        for (int r = 0; r < 4; ++r) {
          const int row = Bg + tq * 4 + r;
          float o = acc_o[r] + bo;
          o = (o >= 0.f) ? o : 0.01f * o;
          out[((size_t)(t - 1) * NB + row) * NO + Ow + tn] = o;
        }
      }
      if (t == SEQ - 1) {
#pragma unroll
        for (int r = 0; r < 4; ++r) {
          const int row = Bg + tq * 4 + r;
          out[(size_t)SEQ * NB * NO + row * NH + Jw + tn] = hv[r];
        }
      }
    }
  }

  // ---- epilogue: o_{SEQ-1} from h_SEQ (parity 0, tag K(SEQ)=4) ----
  if (!sh_dead) {
    const float Kt = kc(SEQ);
    const float* hP = hb + (SEQ & 1) * 65536;
    unsigned long long q[32];
    int iter = 0;
    while (true) {
#pragma unroll
      for (int c = 0; c < 8; ++c) {
        const unsigned long long* p = (const unsigned long long*)(hP + rowoff + c * 32);
#pragma unroll
        for (int u = 0; u < 4; ++u)
          q[4 * c + u] = __hip_atomic_load(p + u, __ATOMIC_RELAXED,
                                           __HIP_MEMORY_SCOPE_AGENT);
      }
      float mn = 1e30f, mx = -1e30f;
#pragma unroll
      for (int i = 0; i < 32; ++i) {
        float f0 = __builtin_bit_cast(float, (unsigned)(q[i] & 0xffffffffull));
        float f1 = __builtin_bit_cast(float, (unsigned)(q[i] >> 32));
        mn = fminf(mn, fminf(f0, f1));
        mx = fmaxf(mx, fmaxf(f0, f1));
      }
      bool ok = (mn > Kt - 2.0f) && (mx < Kt + 2.0f);
      if (__all(ok)) break;
      if (++iter > SPIN_LIM) break;
    }
    f32x4 acc_o = {0.f, 0.f, 0.f, 0.f};
#pragma unroll
    for (int c = 0; c < 8; ++c) {
      bf16x8 ahi, alo;
#pragma unroll
      for (int u = 0; u < 4; ++u) {
        unsigned long long qq = q[4 * c + u];
        float f0 = __builtin_bit_cast(float, (unsigned)(qq & 0xffffffffull)) - Kt;
        float f1 = __builtin_bit_cast(float, (unsigned)(qq >> 32)) - Kt;
        __bf16 b0 = (__bf16)f0;
        ahi[2 * u] = b0; alo[2 * u] = (__bf16)(f0 - (float)b0);
        __bf16 b1 = (__bf16)f1;
        ahi[2 * u + 1] = b1; alo[2 * u + 1] = (__bf16)(f1 - (float)b1);
      }
      acc_o = mfma16(ahi, hof[c], acc_o);
      acc_o = mfma16(alo, hof[c], acc_o);
    }
    if (wv > 0) {
#pragma unroll
      for (int r = 0; r < 4; ++r) red_o[0][wv - 1][r * 64 + lane] = acc_o[r];
    }
    __syncthreads();
    if (wv == 0 && tn < 8) {
#pragma unroll
      for (int r = 0; r < 4; ++r) {
        float s = acc_o[r];
#pragma unroll
        for (int p = 0; p < 3; ++p) s += red_o[0][p][r * 64 + lane];
        const int row = Bg + tq * 4 + r;
        float o = s + bo;
        o = (o >= 0.f) ? o : 0.01f * o;
        out[((size_t)(SEQ - 1) * NB + row) * NO + Ow + tn] = o;
      }
    }
  }
}

extern "C" void kernel_launch(void* const* d_in, const int* in_sizes, int n_in,
                              void* d_out, int out_size, void* d_ws, size_t ws_size,
                              hipStream_t stream) {
  (void)in_sizes; (void)n_in; (void)out_size; (void)ws_size;
  const float* x   = (const float*)d_in[0];
  const float* h0  = (const float*)d_in[1];
  const float* i_h = (const float*)d_in[2];
  const float* h_h = (const float*)d_in[3];
  const float* h_o = (const float*)d_in[4];
  const float* b_i = (const float*)d_in[5];
  const float* b_o = (const float*)d_in[6];
  float* out = (float*)d_out;
  float* hbuf = (float*)d_ws;  // [2][64][1024] fp32 = 512 KB; 0xAA poison
                               // self-rejects, so no memset needed.

  void* args[] = {&x, &h0, &i_h, &h_h, &h_o, &b_i, &b_o, &out, &hbuf};
  hipError_t err = hipLaunchCooperativeKernel((const void*)rnn_vt,
                                              dim3(256), dim3(256), args, 0, stream);
  if (err != hipSuccess) {
    // Plain launch fallback: grid 256 <= 1 block/CU capacity -> co-resident.
    rnn_vt<<<dim3(256), dim3(256), 0, stream>>>(
        x, h0, i_h, h_h, h_o, b_i, b_o, out, hbuf);
  }
}